// Round 3
// baseline (404.667 us; speedup 1.0000x reference)
//
#include <hip/hip_runtime.h>
#include <stdint.h>

// BinaryLinearLayer: out = sign(x) @ sign(w), x:[8192,4096] f32, w:[4096,4096] f32.
// Exact path via i8 MFMA (K-sums <= 4096, exact in i32).
// R3: replace XOR-swizzle (4-way conflicts w/ 32-row frags, SQ_LDS_BANK_CONFLICT
// =1.26e7 = ~20us/CU of port serialization) with an MFMA-native blocked LDS
// layout: (32row x 32kB) blocks of 1024B, lane l of a frag ds_read_b128 at
// block + ((l&31)*2 + l>>5)*16 -> contiguous 1024B per wave instr = zero
// conflicts + offset:-foldable addresses. global_load_lds dest stays linear;
// per-lane global source carries the permutation (both-sides rule).

#define DIN  4096
#define DOUT 4096
#define BM   256
#define BN   256
#define BK   128            // i8 k-elems per LDS K-tile = 128B rows
#define NT   (DIN / BK)     // 32 K-tiles

typedef __attribute__((ext_vector_type(4)))  int v4i;
typedef __attribute__((ext_vector_type(16))) int v16i;
typedef unsigned int u32;

__device__ __forceinline__ void cp16(void* lds, const void* g) {
    __builtin_amdgcn_global_load_lds((const __attribute__((address_space(1))) u32*)g,
                                     (__attribute__((address_space(3))) u32*)lds,
                                     16, 0, 0);
}

// ---- x [N,DIN] f32 -> xb [N,DIN] i8 (+1/-1): 64B read / 16B write per thread ----
__global__ __launch_bounds__(256) void pack_x_i8(const float* __restrict__ x,
                                                 signed char* __restrict__ xb) {
    size_t g = (size_t)blockIdx.x * 256 + threadIdx.x;   // 16-float group index
    const float4* xv = (const float4*)x + g * 4;
    v4i o;
    #pragma unroll
    for (int q = 0; q < 4; q++) {
        float4 v = xv[q];
        int c0 = v.x >= 0.f ? 1 : 0xFF;
        int c1 = v.y >= 0.f ? 1 : 0xFF;
        int c2 = v.z >= 0.f ? 1 : 0xFF;
        int c3 = v.w >= 0.f ? 1 : 0xFF;
        o[q] = c0 | (c1 << 8) | (c2 << 16) | (c3 << 24);
    }
    ((v4i*)xb)[g] = o;
}

// ---- w [DIN,DOUT] f32 -> wbT [DOUT,DIN] i8: wbT[n][k] = sign(w[k][n]) ----
__global__ __launch_bounds__(256) void pack_wT_i8(const float* __restrict__ w,
                                                  signed char* __restrict__ wbT) {
    __shared__ signed char tile[64][80];   // stride 80: 16B-aligned rows, breaks pow2
    const int k0 = blockIdx.y * 64, n0 = blockIdx.x * 64;
    const int t = threadIdx.x;
    const int j4 = (t & 15) * 4;    // n offset (float4)
    const int i0 = t >> 4;          // k row 0..15
    #pragma unroll
    for (int s = 0; s < 4; s++) {
        int i = i0 + s * 16;        // k offset
        float4 v = *(const float4*)&w[(size_t)(k0 + i) * DOUT + n0 + j4];
        tile[j4 + 0][i] = v.x >= 0.f ? 1 : -1;
        tile[j4 + 1][i] = v.y >= 0.f ? 1 : -1;
        tile[j4 + 2][i] = v.z >= 0.f ? 1 : -1;
        tile[j4 + 3][i] = v.w >= 0.f ? 1 : -1;
    }
    __syncthreads();
    const int n  = t >> 2;          // 0..63
    const int kk = (t & 3) * 16;    // byte offset within row
    v4i val = *(const v4i*)&tile[n][kk];
    *(v4i*)&wbT[(size_t)(n0 + n) * DIN + k0 + kk] = val;
}

// ---- 256^2 8-wave 2-phase/K-tile i8 MFMA GEMM (32x32x32), blocked LDS ----
// 512 thr = 8 waves (2M x 4N); per-wave C = 128x64 = 4x2 frags of 32x32.
// LDS tile layout: block(R32 = row>>5, ks = kbyte>>5) at (R32*4+ks)*1024;
// within: (row&31)*32 + hi*16. Frag read = contiguous 1024B/wave (0 conflicts).
// Staging unit = 64 rows (8KB, 512 cp16): thread t -> LDS t*16 = block(t>>8,
// (t>>6)&3), lane (lm = (t&63)>>1, hi = t&1) -> global row (t>>8&1)*32+lm,
// col ks*32+hi*16.  Phases/vmcnt identical to R2 (verified):
// p0:[B0,B64,B128,B192] p1:[A0,A128,A64,A192]; vmcnt(4)@p0-end, vmcnt(2)@p1-end.
__global__ __launch_bounds__(512, 2) void bgemm_i8(const signed char* __restrict__ xb,
                                                   const signed char* __restrict__ wbT,
                                                   float* __restrict__ out) {
    __shared__ __align__(16) signed char As[2][BM * BK];   // 2 x 32 KB
    __shared__ __align__(16) signed char Bs[2][BN * BK];   // 2 x 32 KB  (128 KB)

    const int t = threadIdx.x;
    const int l = t & 63;
    const int w = t >> 6;          // 8 waves
    const int wr = w & 1;          // A half: rows wr*128..+127 (R32 blocks wr*4..+3)
    const int wc = w >> 1;         // B band: rows wc*64..+63  (R32 blocks wc*2..+1)
    const int lm = l & 31;         // frag row lane
    const int hi = l >> 5;         // k-half
    const int loff = (lm << 5) + (hi << 4);   // in-block lane offset (contig 1024B/wave)

    const int fid = blockIdx.y * gridDim.x + blockIdx.x;
    const int swz = (fid & 7) * 64 + (fid >> 3);
    const int bm = (swz >> 4) * BM, bn = (swz & 15) * BN;

    const signed char* gA = xb  + (size_t)bm * DIN;
    const signed char* gB = wbT + (size_t)bn * DIN;

    // staging source permutation matching the blocked LDS layout
    const int    srow = ((t >> 8) & 1) * 32 + ((t & 63) >> 1);
    const int    scol = ((t >> 6) & 3) * 32 + (t & 1) * 16;
    const size_t soff = (size_t)srow * DIN + scol;
    const int    ldst = t * 16;

#define SU(lbuf, gmat, r0, kk) \
    cp16(&(lbuf)[(r0) * BK + ldst], (gmat) + (size_t)(r0) * DIN + (size_t)(kk) + soff)

    v16i acc[4][2];
    #pragma unroll
    for (int i = 0; i < 4; i++)
        #pragma unroll
        for (int j = 0; j < 2; j++)
            #pragma unroll
            for (int r = 0; r < 16; r++)
                acc[i][j][r] = 0;

    // prologue: K-tile 0 -> buf 0 (steady-state unit order); leave A64/A192 in flight
    SU(Bs[0], gB, 0, 0);   SU(Bs[0], gB, 64, 0);
    SU(Bs[0], gB, 128, 0); SU(Bs[0], gB, 192, 0);
    SU(As[0], gA, 0, 0);   SU(As[0], gA, 128, 0);
    SU(As[0], gA, 64, 0);  SU(As[0], gA, 192, 0);
    asm volatile("s_waitcnt vmcnt(2)" ::: "memory");
    __builtin_amdgcn_s_barrier();

    v4i b[2][4];   // B frags, read in p0, live across the whole K-tile

    for (int kt = 0; kt < NT - 1; ++kt) {
        const int cur = kt & 1, nxt = cur ^ 1;
        const int kk = (kt + 1) * BK;
        #pragma unroll
        for (int p = 0; p < 2; ++p) {
            v4i a[2][4];
            #pragma unroll
            for (int i = 0; i < 2; ++i) {   // m-frag 2p+i -> R32 = wr*4 + 2p+i
                const signed char* ap = &As[cur][(wr * 4 + 2 * p + i) * 4096 + loff];
                #pragma unroll
                for (int ks = 0; ks < 4; ++ks)
                    a[i][ks] = *(const v4i*)(ap + ks * 1024);
            }
            if (p == 0) {
                #pragma unroll
                for (int j = 0; j < 2; ++j) {
                    const signed char* bp = &Bs[cur][(wc * 2 + j) * 4096 + loff];
                    #pragma unroll
                    for (int ks = 0; ks < 4; ++ks)
                        b[j][ks] = *(const v4i*)(bp + ks * 1024);
                }
                SU(Bs[nxt], gB, 0, kk);   SU(Bs[nxt], gB, 64, kk);
                SU(Bs[nxt], gB, 128, kk); SU(Bs[nxt], gB, 192, kk);
            } else {
                SU(As[nxt], gA, 0, kk);   SU(As[nxt], gA, 128, kk);
                SU(As[nxt], gA, 64, kk);  SU(As[nxt], gA, 192, kk);
            }

            __builtin_amdgcn_s_barrier();
            asm volatile("s_waitcnt lgkmcnt(0)" ::: "memory");
            __builtin_amdgcn_sched_barrier(0);
            __builtin_amdgcn_s_setprio(1);
            #pragma unroll
            for (int ks = 0; ks < 4; ++ks)
                #pragma unroll
                for (int i = 0; i < 2; ++i)
                    #pragma unroll
                    for (int j = 0; j < 2; ++j)
                        acc[2 * p + i][j] = __builtin_amdgcn_mfma_i32_32x32x32_i8(
                            a[i][ks], b[j][ks], acc[2 * p + i][j], 0, 0, 0);
            __builtin_amdgcn_s_setprio(0);
            __builtin_amdgcn_sched_barrier(0);
            if (p == 0) asm volatile("s_waitcnt vmcnt(4)" ::: "memory");
            else        asm volatile("s_waitcnt vmcnt(2)" ::: "memory");
            __builtin_amdgcn_s_barrier();
        }
    }

    // peeled last K-tile (no prefetch; drain A64/A192 before p1 reads them)
    {
        const int cur = (NT - 1) & 1;
        #pragma unroll
        for (int p = 0; p < 2; ++p) {
            v4i a[2][4];
            #pragma unroll
            for (int i = 0; i < 2; ++i) {
                const signed char* ap = &As[cur][(wr * 4 + 2 * p + i) * 4096 + loff];
                #pragma unroll
                for (int ks = 0; ks < 4; ++ks)
                    a[i][ks] = *(const v4i*)(ap + ks * 1024);
            }
            if (p == 0) {
                #pragma unroll
                for (int j = 0; j < 2; ++j) {
                    const signed char* bp = &Bs[cur][(wc * 2 + j) * 4096 + loff];
                    #pragma unroll
                    for (int ks = 0; ks < 4; ++ks)
                        b[j][ks] = *(const v4i*)(bp + ks * 1024);
                }
            }
            __builtin_amdgcn_s_barrier();
            asm volatile("s_waitcnt lgkmcnt(0)" ::: "memory");
            __builtin_amdgcn_sched_barrier(0);
            __builtin_amdgcn_s_setprio(1);
            #pragma unroll
            for (int ks = 0; ks < 4; ++ks)
                #pragma unroll
                for (int i = 0; i < 2; ++i)
                    #pragma unroll
                    for (int j = 0; j < 2; ++j)
                        acc[2 * p + i][j] = __builtin_amdgcn_mfma_i32_32x32x32_i8(
                            a[i][ks], b[j][ks], acc[2 * p + i][j], 0, 0, 0);
            __builtin_amdgcn_s_setprio(0);
            __builtin_amdgcn_sched_barrier(0);
            if (p == 0) asm volatile("s_waitcnt vmcnt(0)" ::: "memory");
            __builtin_amdgcn_s_barrier();
        }
    }
#undef SU

    // epilogue: C/D col=l&31, row=(r&3)+8*(r>>2)+4*hi (shape-determined)
    #pragma unroll
    for (int f = 0; f < 4; f++) {
        #pragma unroll
        for (int g = 0; g < 2; g++) {
            int col = bn + wc * 64 + g * 32 + lm;
            #pragma unroll
            for (int r = 0; r < 16; r++) {
                int row = bm + wr * 128 + f * 32 + (r & 3) + 8 * (r >> 2) + 4 * hi;
                out[(size_t)row * DOUT + col] = (float)acc[f][g][r];
            }
        }
    }
}

extern "C" void kernel_launch(void* const* d_in, const int* in_sizes, int n_in,
                              void* d_out, int out_size, void* d_ws, size_t ws_size,
                              hipStream_t stream) {
    const float* x = (const float*)d_in[0];
    const float* w = (const float*)d_in[1];
    float* out = (float*)d_out;
    const int N = in_sizes[0] / DIN;                       // 8192

    signed char* xb  = (signed char*)d_ws;                 // 32 MB
    signed char* wbT = (signed char*)d_ws + (size_t)N * DIN;  // 16 MB

    pack_x_i8<<<(N * DIN) / (16 * 256), 256, 0, stream>>>(x, xb);
    pack_wT_i8<<<dim3(DOUT / 64, DIN / 64), 256, 0, stream>>>(w, wbT);
    bgemm_i8<<<dim3(DOUT / BN, N / BM), 512, 0, stream>>>(xb, wbT, out);
}